// Round 11
// baseline (123.810 us; speedup 1.0000x reference)
//
#include <hip/hip_runtime.h>

// DSAttention round 11: 8-wave blocks (QTL=256). vs r10 (QTL=128, 4 waves):
// half the blocks (prologue amortization), half the per-thread staging work
// (512 threads share each 64-key tile), K/V fetch per FLOP halves, and CH=4
// divides 4qt+4 exactly -> every chunk is exactly 4 iterations (uniform).
// LDS 55.3KB -> 2 blocks/CU x 8 waves = 16 waves/CU capacity.
// Keeps: two-pass PV, prefetch-after-barrier, f16 partials, DPP rowmax,
// MFMA rowsum-ones, launch_bounds that don't cap VGPRs (r8 spill lesson).

typedef _Float16 h8 __attribute__((ext_vector_type(8)));
typedef _Float16 h2 __attribute__((ext_vector_type(2)));
typedef float f32x4 __attribute__((ext_vector_type(4)));

constexpr int Bc = 2, Lc = 2048, Hc = 8, Ec = 64, Sc = 2048;
constexpr int QTL = 256;              // q rows per block (8 waves x 32)
constexpr int NQT = Lc / QTL;         // 8 q-tiles
constexpr int KT = 64;                // keys per staged tile
constexpr int LDK = 72;               // LDS row stride (halfs), 144B 16B-aligned
constexpr float SCALE = 0.125f;
constexpr float LOG2E = 1.44269504088896340736f;

__device__ __forceinline__ h2 pk2(float x, float y) {
  return __builtin_bit_cast(h2, __builtin_amdgcn_cvt_pkrtz(x, y));
}
template <int CTRL>
__device__ __forceinline__ float dpp_f(float x) {
  int r = __builtin_amdgcn_update_dpp(0, __builtin_bit_cast(int, x), CTRL, 0xF, 0xF, true);
  return __builtin_bit_cast(float, r);
}
__device__ __forceinline__ float rowmax16(float x) {
  x = fmaxf(x, dpp_f<0xB1>(x));    // xor 1 (quad_perm)
  x = fmaxf(x, dpp_f<0x4E>(x));    // xor 2 (quad_perm)
  x = fmaxf(x, dpp_f<0x124>(x));   // row_ror:4
  x = fmaxf(x, dpp_f<0x128>(x));   // row_ror:8
  return x;
}

// CH_IT = kt-tiles per chunk (4 = split; 32 = monolithic fallback)
template <int CH_IT, int EPB>
__global__ __launch_bounds__(512, 2)
void dsattn_fwd(const float* __restrict__ Qg, const float* __restrict__ Kg,
                const float* __restrict__ Vg, const float* __restrict__ taug,
                const float* __restrict__ deltag, float* __restrict__ Og,
                _Float16* __restrict__ Opart, float* __restrict__ Mpart,
                float* __restrict__ Lpart) {
  __shared__ __align__(16) _Float16 Ks[2][KT * LDK];   // 18432 B
  __shared__ __align__(16) _Float16 Vt[2][Ec * LDK];   // 18432 B
  __shared__ __align__(16) _Float16 Pb[8][16 * LDK];   // 18432 B -> 55296 total

  // ---- compact (qt, chunk) enumeration, biggest-work-first ----
  int qt = NQT - 1, c0 = 0, pre_e = 0;
  if (CH_IT < 4 * NQT) {
    int bxx = (int)blockIdx.x;
#pragma unroll
    for (int q = NQT - 1; q >= 0; --q) {
      const int n = (4 * q + 3 + CH_IT) / CH_IT;   // nch(q), ntiles=4q+4
      if (bxx < n) { qt = q; c0 = bxx; break; }
      bxx -= n;
    }
#pragma unroll
    for (int q = 0; q < NQT; ++q)
      if (q < qt) pre_e += (4 * q + 3 + CH_IT) / CH_IT;
  } else {
    qt = NQT - 1 - (int)blockIdx.x;
  }
  const int ntiles = 4 * qt + 4;
  const int nch = (ntiles + CH_IT - 1) / CH_IT;
  const int ktBeg = c0 * CH_IT;
  const int ktEnd = min(ktBeg + CH_IT - 1, ntiles - 1);

  const int tid = threadIdx.x;
  const int wave = tid >> 6, lane = tid & 63;
  const int quad = lane >> 4, l16 = lane & 15;
  const int q0 = qt * QTL;
  const int bh = (int)blockIdx.y;
  const int b = bh >> 3, h = bh & 7;
  const float ct = taug[b] * (SCALE * LOG2E);

  // ---- Q A-fragments: frag f covers rows q0+32*wave+16f+l16 ----
  h8 qfrag[2][2];
#pragma unroll
  for (int f = 0; f < 2; ++f)
#pragma unroll
    for (int kk = 0; kk < 2; ++kk) {
      const float* qp = Qg + (((size_t)b * Lc + q0 + 32 * wave + 16 * f + l16) * Hc + h) * Ec
                       + quad * 8 + kk * 32;
      const float4* p = (const float4*)qp;
      union { h8 v; h2 c[4]; } u;
      float4 a0 = p[0], a1 = p[1];
      u.c[0] = pk2(a0.x, a0.y); u.c[1] = pk2(a0.z, a0.w);
      u.c[2] = pk2(a1.x, a1.y); u.c[3] = pk2(a1.z, a1.w);
      qfrag[f][kk] = u.v;
    }

  h8 onesf;
#pragma unroll
  for (int j = 0; j < 8; ++j) onesf[j] = (_Float16)1.0f;

  f32x4 Oacc[2][4], Osum[2];
  float mrow[2][4];
#pragma unroll
  for (int f = 0; f < 2; ++f) {
#pragma unroll
    for (int nt = 0; nt < 4; ++nt) Oacc[f][nt] = (f32x4){0.f, 0.f, 0.f, 0.f};
    Osum[f] = (f32x4){0.f, 0.f, 0.f, 0.f};
#pragma unroll
    for (int r = 0; r < 4; ++r) mrow[f][r] = -1e30f;
  }

  // staging assignments (512 threads)
  const int srow = tid >> 3;                           // K: row 0..63
  const int sec = (tid & 7) << 3;                      // K: e-chunk of 8
  const int vrp = ((tid >> 4) + 2 * (tid & 15)) & 31;  // V: row-pair (swizzled)
  const int ve4 = (tid & 15) << 2;                     // V: e-chunk of 4

  _Float16* pb = &Pb[wave][0];
  const int lo = l16 & 1;
  const int pbase = (lo ? 32 : 0) + (l16 & ~1);
  float dcur[4];

  // ---- prologue: stage tile ktBeg into buffer 0 ----
  {
    const int kb = ktBeg * KT;
    const float* kp = Kg + (((size_t)b * Sc + kb + srow) * Hc + h) * Ec + sec;
    float4 c0v = ((const float4*)kp)[0], c1v = ((const float4*)kp)[1];
    const float* vp0 = Vg + (((size_t)b * Sc + kb + 2 * vrp) * Hc + h) * Ec + ve4;
    const float* vp1 = vp0 + Hc * Ec;
    float4 r0 = *(const float4*)vp0;
    float4 r1 = *(const float4*)vp1;
#pragma unroll
    for (int nt = 0; nt < 4; ++nt)
      dcur[nt] = deltag[(size_t)b * Sc + kb + nt * 16 + l16] * (SCALE * LOG2E);
    union { h8 v; h2 c[4]; } w0;
    w0.c[0] = pk2(c0v.x, c0v.y); w0.c[1] = pk2(c0v.z, c0v.w);
    w0.c[2] = pk2(c1v.x, c1v.y); w0.c[3] = pk2(c1v.z, c1v.w);
    *(h8*)&Ks[0][srow * LDK + sec] = w0.v;
    const float e0[4] = {r0.x, r0.y, r0.z, r0.w};
    const float e1[4] = {r1.x, r1.y, r1.z, r1.w};
#pragma unroll
    for (int j = 0; j < 4; ++j)
      *(h2*)&Vt[0][(ve4 + j) * LDK + 2 * vrp] = pk2(e0[j], e1[j]);
  }

  for (int kt = ktBeg; kt <= ktEnd; ++kt) {
    const int cur = (kt - ktBeg) & 1;
    const bool pf = (kt < ktEnd);
    const int kbase = kt * KT;

    __syncthreads();   // buffer cur ready; vmcnt naturally drained

    // ---- prefetch kt+1 AFTER the barrier; consumed at iteration end ----
    float4 kn0, kn1, vn0, vn1;
    float dn[4];
    if (pf) {
      const int nb = (kt + 1) * KT;
      const float* kp = Kg + (((size_t)b * Sc + nb + srow) * Hc + h) * Ec + sec;
      kn0 = ((const float4*)kp)[0]; kn1 = ((const float4*)kp)[1];
      const float* vp0 = Vg + (((size_t)b * Sc + nb + 2 * vrp) * Hc + h) * Ec + ve4;
      const float* vp1 = vp0 + Hc * Ec;
      vn0 = *(const float4*)vp0;
      vn1 = *(const float4*)vp1;
#pragma unroll
      for (int nt = 0; nt < 4; ++nt)
        dn[nt] = deltag[(size_t)b * Sc + nb + nt * 16 + l16];
    }

    // wave-uniform: skip compute for tiles fully above this wave's rows
    const int wtop = q0 + 32 * wave + 31;
    if (kbase <= wtop) {
      // ---- S = Q.K^T (K B-frags read once, shared by both frags) ----
      f32x4 Sacc[2][4];
#pragma unroll
      for (int f = 0; f < 2; ++f)
#pragma unroll
        for (int nt = 0; nt < 4; ++nt) Sacc[f][nt] = (f32x4){0.f, 0.f, 0.f, 0.f};
#pragma unroll
      for (int kk = 0; kk < 2; ++kk) {
        h8 bf[4];
#pragma unroll
        for (int nt = 0; nt < 4; ++nt)
          bf[nt] = *(const h8*)&Ks[cur][(nt * 16 + l16) * LDK + quad * 8 + kk * 32];
#pragma unroll
        for (int f = 0; f < 2; ++f)
#pragma unroll
          for (int nt = 0; nt < 4; ++nt)
            Sacc[f][nt] = __builtin_amdgcn_mfma_f32_16x16x32_f16(qfrag[f][kk], bf[nt], Sacc[f][nt], 0, 0, 0);
      }

      // ---- two passes: softmax(f) -> P(f) -> PV(f) (Pb is 16 rows/wave) ----
#pragma unroll
      for (int f = 0; f < 2; ++f) {
        const int fr0 = q0 + 32 * wave + 16 * f;
        float sv[4][4];
#pragma unroll
        for (int nt = 0; nt < 4; ++nt)
#pragma unroll
          for (int r = 0; r < 4; ++r)
            sv[nt][r] = Sacc[f][nt][r] * ct + dcur[nt];
        if (kbase + 63 > fr0) {
#pragma unroll
          for (int nt = 0; nt < 4; ++nt) {
            const int key = kbase + nt * 16 + l16;
#pragma unroll
            for (int r = 0; r < 4; ++r)
              if (key > fr0 + quad * 4 + r) sv[nt][r] = -1e30f;
          }
        }
#pragma unroll
        for (int r = 0; r < 4; ++r) {
          float tm = fmaxf(fmaxf(sv[0][r], sv[1][r]), fmaxf(sv[2][r], sv[3][r]));
          tm = rowmax16(tm);
          float mn = fmaxf(mrow[f][r], tm);
          float alpha = __builtin_amdgcn_exp2f(mrow[f][r] - mn);
          mrow[f][r] = mn;
#pragma unroll
          for (int nt = 0; nt < 4; ++nt)
            sv[nt][r] = __builtin_amdgcn_exp2f(sv[nt][r] - mn);
          Osum[f][r] *= alpha;
#pragma unroll
          for (int nt = 0; nt < 4; ++nt) Oacc[f][nt][r] *= alpha;
        }
        // P -> LDS rows quad*4+r (within-wave LDS in-order: WAR safe)
#pragma unroll
        for (int r = 0; r < 4; ++r) {
          float o0 = dpp_f<0xB1>(sv[0][r]);
          float o1 = dpp_f<0xB1>(sv[1][r]);
          float o2 = dpp_f<0xB1>(sv[2][r]);
          float o3 = dpp_f<0xB1>(sv[3][r]);
          h2 d0 = lo ? pk2(o2, sv[2][r]) : pk2(sv[0][r], o0);
          h2 d1 = lo ? pk2(o3, sv[3][r]) : pk2(sv[1][r], o1);
          _Float16* pp = &pb[((quad << 2) + r) * LDK + pbase];
          *(h2*)pp = d0;
          *(h2*)(pp + 16) = d1;
        }
        asm volatile("s_waitcnt lgkmcnt(0)" ::: "memory");  // wave-local P RAW

        h8 af0 = *(const h8*)&pb[l16 * LDK + quad * 8];
        h8 af1 = *(const h8*)&pb[l16 * LDK + quad * 8 + 32];

#pragma unroll
        for (int nt = 0; nt < 4; ++nt) {
          h8 vf0 = *(const h8*)&Vt[cur][(nt * 16 + l16) * LDK + quad * 8];
          Oacc[f][nt] = __builtin_amdgcn_mfma_f32_16x16x32_f16(af0, vf0, Oacc[f][nt], 0, 0, 0);
          h8 vf1 = *(const h8*)&Vt[cur][(nt * 16 + l16) * LDK + quad * 8 + 32];
          Oacc[f][nt] = __builtin_amdgcn_mfma_f32_16x16x32_f16(af1, vf1, Oacc[f][nt], 0, 0, 0);
        }
        Osum[f] = __builtin_amdgcn_mfma_f32_16x16x32_f16(af0, onesf, Osum[f], 0, 0, 0);
        Osum[f] = __builtin_amdgcn_mfma_f32_16x16x32_f16(af1, onesf, Osum[f], 0, 0, 0);
      }
    }

    // ---- write prefetched tile kt+1 into the other buffer ----
    if (pf) {
      _Float16* ksn = &Ks[cur ^ 1][0];
      _Float16* vtn = &Vt[cur ^ 1][0];
      union { h8 v; h2 c[4]; } w0;
      w0.c[0] = pk2(kn0.x, kn0.y); w0.c[1] = pk2(kn0.z, kn0.w);
      w0.c[2] = pk2(kn1.x, kn1.y); w0.c[3] = pk2(kn1.z, kn1.w);
      *(h8*)&ksn[srow * LDK + sec] = w0.v;
      const float e0[4] = {vn0.x, vn0.y, vn0.z, vn0.w};
      const float e1[4] = {vn1.x, vn1.y, vn1.z, vn1.w};
#pragma unroll
      for (int j = 0; j < 4; ++j)
        *(h2*)&vtn[(ve4 + j) * LDK + 2 * vrp] = pk2(e0[j], e1[j]);
#pragma unroll
      for (int nt = 0; nt < 4; ++nt) dcur[nt] = dn[nt] * (SCALE * LOG2E);
    }
  }

  // ---- epilogue ----
  if (nch == 1) {
#pragma unroll
    for (int f = 0; f < 2; ++f)
#pragma unroll
      for (int r = 0; r < 4; ++r) {
        const int qrow = q0 + 32 * wave + 16 * f + (quad << 2) + r;
        const float inv = 1.0f / Osum[f][r];
        float* op = Og + (((size_t)b * Lc + qrow) * Hc + h) * Ec;
#pragma unroll
        for (int nt = 0; nt < 4; ++nt) op[nt * 16 + l16] = Oacc[f][nt][r] * inv;
      }
  } else {
    const int e = bh * EPB + pre_e + c0;
    _Float16* op = Opart + (size_t)e * (QTL * Ec);
#pragma unroll
    for (int f = 0; f < 2; ++f)
#pragma unroll
      for (int r = 0; r < 4; ++r) {
        const int row = 32 * wave + 16 * f + (quad << 2) + r;
#pragma unroll
        for (int nt = 0; nt < 4; ++nt)
          op[row * Ec + nt * 16 + l16] = (_Float16)Oacc[f][nt][r];
        if (l16 == 0) {
          Mpart[e * QTL + row] = mrow[f][r];
          Lpart[e * QTL + row] = Osum[f][r];
        }
      }
  }
}

template <int CH_IT, int EPB>
__global__ __launch_bounds__(256, 4)
void dsattn_comb(const _Float16* __restrict__ Opart, const float* __restrict__ Mpart,
                 const float* __restrict__ Lpart, float* __restrict__ Og) {
  const int qt = 1 + ((int)blockIdx.x >> 3);    // qtiles 1..7 (nch >= 2)
  const int slab = (int)blockIdx.x & 7;         // 32-row slab (8 per qtile)
  const int bh = (int)blockIdx.y;
  const int b = bh >> 3, h = bh & 7;
  const int nch = (4 * qt + 3 + CH_IT) / CH_IT; // 2..8
  int pre_e = 0;
#pragma unroll
  for (int q = 0; q < NQT; ++q)
    if (q < qt) pre_e += (4 * q + 3 + CH_IT) / CH_IT;
  const int e0 = bh * EPB + pre_e;

  const int row = slab * 32 + ((int)threadIdx.x >> 3);  // 0..255
  const int col = ((int)threadIdx.x & 7) << 3;          // 8 cols per thread

  float ms[8];
  float M = -1e30f;
  for (int c = 0; c < nch; ++c) {
    ms[c] = Mpart[(e0 + c) * QTL + row];
    M = fmaxf(M, ms[c]);
  }
  float acc[8];
#pragma unroll
  for (int i = 0; i < 8; ++i) acc[i] = 0.f;
  float l = 0.f;
  for (int c = 0; c < nch; ++c) {
    const float w = __builtin_amdgcn_exp2f(ms[c] - M);
    l += w * Lpart[(e0 + c) * QTL + row];
    h8 v = *(const h8*)(Opart + (size_t)(e0 + c) * (QTL * Ec) + row * Ec + col);
#pragma unroll
    for (int i = 0; i < 8; ++i) acc[i] += w * (float)v[i];
  }
  const float inv = 1.0f / l;
  float* out = Og + (((size_t)b * Lc + qt * QTL + row) * Hc + h) * Ec + col;
  float4 o0, o1;
  o0.x = acc[0] * inv; o0.y = acc[1] * inv; o0.z = acc[2] * inv; o0.w = acc[3] * inv;
  o1.x = acc[4] * inv; o1.y = acc[5] * inv; o1.z = acc[6] * inv; o1.w = acc[7] * inv;
  ((float4*)out)[0] = o0;
  ((float4*)out)[1] = o1;
}

extern "C" void kernel_launch(void* const* d_in, const int* in_sizes, int n_in,
                              void* d_out, int out_size, void* d_ws, size_t ws_size,
                              hipStream_t stream) {
  const float* Q = (const float*)d_in[0];
  const float* K = (const float*)d_in[1];
  const float* V = (const float*)d_in[2];
  const float* tau = (const float*)d_in[3];
  const float* delta = (const float*)d_in[4];
  float* O = (float*)d_out;

  constexpr int CH = 4;                    // kt-tiles per chunk (256 keys)
  constexpr int EPB = 36;                  // sum of nch(qt)=qt+1 over 8 q-tiles
  constexpr int TOT_E = Bc * Hc * EPB;     // 576 entries
  const size_t need = (size_t)TOT_E * QTL * Ec * 2 + 2 * (size_t)TOT_E * QTL * 4;

  if (ws_size >= need) {
    _Float16* Opart = (_Float16*)d_ws;
    float* Mpart = (float*)(Opart + (size_t)TOT_E * QTL * Ec);
    float* Lpart = Mpart + (size_t)TOT_E * QTL;
    dim3 g1(EPB, Bc * Hc);                 // exact (qt,chunk) enumeration
    dsattn_fwd<CH, EPB><<<g1, 512, 0, stream>>>(Q, K, V, tau, delta, O,
                                                Opart, Mpart, Lpart);
    dim3 g2((NQT - 1) * 8, Bc * Hc);       // 8 row-slabs per multi-chunk q-tile
    dsattn_comb<CH, EPB><<<g2, 256, 0, stream>>>(Opart, Mpart, Lpart, O);
  } else {
    dim3 g1(NQT, Bc * Hc);                 // monolithic fallback
    dsattn_fwd<32, 1><<<g1, 512, 0, stream>>>(Q, K, V, tau, delta, O,
                                              nullptr, nullptr, nullptr);
  }
}

// Round 12
// 115.840 us; speedup vs baseline: 1.0688x; 1.0688x over previous
//
#include <hip/hip_runtime.h>

// DSAttention round 12: persistent work-loop kernel. Body = r10 (best fwd:
// 43.5us — QTL=128, 4 waves, CH=4, two-pass PV, LDS 46080B, VGPR 104 no-spill).
// Change: grid is exactly 768 blocks (3/CU capacity); each block loops over
// flattened (qt,chunk,bh) work items (wid += gridDim.x). Removes dispatch
// churn / retire-refill gaps — tests & fixes the packing starvation that kept
// time-avg residency at 1.2 blocks/CU despite 3/CU capacity.

typedef _Float16 h8 __attribute__((ext_vector_type(8)));
typedef _Float16 h2 __attribute__((ext_vector_type(2)));
typedef float f32x4 __attribute__((ext_vector_type(4)));

constexpr int Bc = 2, Lc = 2048, Hc = 8, Ec = 64, Sc = 2048;
constexpr int QTL = 128;              // q rows per block-item
constexpr int NQT = Lc / QTL;         // 16 q-tiles
constexpr int KT = 64;                // keys per staged tile
constexpr int LDK = 72;               // LDS row stride (halfs), 144B 16B-aligned
constexpr int NBH = Bc * Hc;          // 16
constexpr float SCALE = 0.125f;
constexpr float LOG2E = 1.44269504088896340736f;

__device__ __forceinline__ h2 pk2(float x, float y) {
  return __builtin_bit_cast(h2, __builtin_amdgcn_cvt_pkrtz(x, y));
}
template <int CTRL>
__device__ __forceinline__ float dpp_f(float x) {
  int r = __builtin_amdgcn_update_dpp(0, __builtin_bit_cast(int, x), CTRL, 0xF, 0xF, true);
  return __builtin_bit_cast(float, r);
}
__device__ __forceinline__ float rowmax16(float x) {
  x = fmaxf(x, dpp_f<0xB1>(x));    // xor 1 (quad_perm)
  x = fmaxf(x, dpp_f<0x4E>(x));    // xor 2 (quad_perm)
  x = fmaxf(x, dpp_f<0x124>(x));   // row_ror:4
  x = fmaxf(x, dpp_f<0x128>(x));   // row_ror:8
  return x;
}

// CH_IT = kt-tiles per chunk; EPB = work entries per (b,h); NIT = total items
template <int CH_IT, int EPB, int NIT>
__global__ __launch_bounds__(256, 2)
void dsattn_fwd(const float* __restrict__ Qg, const float* __restrict__ Kg,
                const float* __restrict__ Vg, const float* __restrict__ taug,
                const float* __restrict__ deltag, float* __restrict__ Og,
                _Float16* __restrict__ Opart, float* __restrict__ Mpart,
                float* __restrict__ Lpart) {
  __shared__ __align__(16) _Float16 Ks[2][KT * LDK];   // 18432 B
  __shared__ __align__(16) _Float16 Vt[2][Ec * LDK];   // 18432 B
  __shared__ __align__(16) _Float16 Pb[4][16 * LDK];   //  9216 B -> 46080 total

  const int tid = threadIdx.x;
  const int wave = tid >> 6, lane = tid & 63;
  const int quad = lane >> 4, l16 = lane & 15;
  const int srow = tid >> 2;
  const int sec = (tid & 3) << 4;
  const int vrp = ((tid >> 3) + 4 * (tid & 7)) & 31;
  const int ve8 = (tid & 7) << 3;
  _Float16* pb = &Pb[wave][0];
  const int lo = l16 & 1;
  const int pbase = (lo ? 32 : 0) + (l16 & ~1);

  h8 onesf;
#pragma unroll
  for (int j = 0; j < 8; ++j) onesf[j] = (_Float16)1.0f;

  // ---- persistent loop over flattened work items (big-first within each e) ----
  for (int wid = (int)blockIdx.x; wid < NIT; wid += (int)gridDim.x) {
    const int bh = wid & (NBH - 1);
    const int e = wid >> 4;              // [0, EPB)
    // decode e -> (qt, c0, pre_e); e enumerates qt descending, chunks ascending
    int qt = NQT - 1, c0 = 0, pre_e = 0;
    {
      int ee = e, acc = 0;
#pragma unroll
      for (int q = NQT - 1; q >= 0; --q) {
        const int n = (2 * q + 1 + CH_IT) / CH_IT;    // nch(q)
        if (ee < n) { qt = q; c0 = ee; pre_e = EPB - acc - n; break; }
        ee -= n; acc += n;
      }
    }
    const int ntiles = 2 * qt + 2;
    const int nch = (ntiles + CH_IT - 1) / CH_IT;
    const int ktBeg = c0 * CH_IT;
    const int ktEnd = min(ktBeg + CH_IT - 1, ntiles - 1);
    const int q0 = qt * QTL;
    const int b = bh >> 3, h = bh & 7;
    const float ct = taug[b] * (SCALE * LOG2E);

    // ---- Q A-fragments: frag f covers rows q0+32*wave+16f+l16 ----
    h8 qfrag[2][2];
#pragma unroll
    for (int f = 0; f < 2; ++f)
#pragma unroll
      for (int kk = 0; kk < 2; ++kk) {
        const float* qp = Qg + (((size_t)b * Lc + q0 + 32 * wave + 16 * f + l16) * Hc + h) * Ec
                         + quad * 8 + kk * 32;
        const float4* p = (const float4*)qp;
        union { h8 v; h2 c[4]; } u;
        float4 a0 = p[0], a1 = p[1];
        u.c[0] = pk2(a0.x, a0.y); u.c[1] = pk2(a0.z, a0.w);
        u.c[2] = pk2(a1.x, a1.y); u.c[3] = pk2(a1.z, a1.w);
        qfrag[f][kk] = u.v;
      }

    f32x4 Oacc[2][4], Osum[2];
    float mrow[2][4];
#pragma unroll
    for (int f = 0; f < 2; ++f) {
#pragma unroll
      for (int nt = 0; nt < 4; ++nt) Oacc[f][nt] = (f32x4){0.f, 0.f, 0.f, 0.f};
      Osum[f] = (f32x4){0.f, 0.f, 0.f, 0.f};
#pragma unroll
      for (int r = 0; r < 4; ++r) mrow[f][r] = -1e30f;
    }

    float dcur[4];

    __syncthreads();   // previous item's LDS reads complete before restaging

    // ---- prologue: stage tile ktBeg into buffer 0 ----
    {
      const int kb = ktBeg * KT;
      const float* kp = Kg + (((size_t)b * Sc + kb + srow) * Hc + h) * Ec + sec;
      float4 c0v = ((const float4*)kp)[0], c1v = ((const float4*)kp)[1];
      float4 c2v = ((const float4*)kp)[2], c3v = ((const float4*)kp)[3];
      const float* vp0 = Vg + (((size_t)b * Sc + kb + 2 * vrp) * Hc + h) * Ec + ve8;
      const float* vp1 = vp0 + Hc * Ec;
      float4 r00 = ((const float4*)vp0)[0], r01 = ((const float4*)vp0)[1];
      float4 r10 = ((const float4*)vp1)[0], r11 = ((const float4*)vp1)[1];
#pragma unroll
      for (int nt = 0; nt < 4; ++nt)
        dcur[nt] = deltag[(size_t)b * Sc + kb + nt * 16 + l16] * (SCALE * LOG2E);
      union { h8 v; h2 c[4]; } w0, w1;
      w0.c[0] = pk2(c0v.x, c0v.y); w0.c[1] = pk2(c0v.z, c0v.w);
      w0.c[2] = pk2(c1v.x, c1v.y); w0.c[3] = pk2(c1v.z, c1v.w);
      w1.c[0] = pk2(c2v.x, c2v.y); w1.c[1] = pk2(c2v.z, c2v.w);
      w1.c[2] = pk2(c3v.x, c3v.y); w1.c[3] = pk2(c3v.z, c3v.w);
      *(h8*)&Ks[0][srow * LDK + sec] = w0.v;
      *(h8*)&Ks[0][srow * LDK + sec + 8] = w1.v;
      const float e0[8] = {r00.x, r00.y, r00.z, r00.w, r01.x, r01.y, r01.z, r01.w};
      const float e1[8] = {r10.x, r10.y, r10.z, r10.w, r11.x, r11.y, r11.z, r11.w};
#pragma unroll
      for (int j = 0; j < 8; ++j)
        *(h2*)&Vt[0][(ve8 + j) * LDK + 2 * vrp] = pk2(e0[j], e1[j]);
    }

    for (int kt = ktBeg; kt <= ktEnd; ++kt) {
      const int cur = (kt - ktBeg) & 1;
      const bool pf = (kt < ktEnd);
      const int kbase = kt * KT;

      __syncthreads();   // buffer cur ready; vmcnt naturally drained

      // ---- prefetch kt+1 AFTER the barrier; consumed at iteration end ----
      float4 kn0, kn1, kn2, kn3, vn00, vn01, vn10, vn11;
      float dn[4];
      if (pf) {
        const int nb = (kt + 1) * KT;
        const float* kp = Kg + (((size_t)b * Sc + nb + srow) * Hc + h) * Ec + sec;
        kn0 = ((const float4*)kp)[0]; kn1 = ((const float4*)kp)[1];
        kn2 = ((const float4*)kp)[2]; kn3 = ((const float4*)kp)[3];
        const float* vp0 = Vg + (((size_t)b * Sc + nb + 2 * vrp) * Hc + h) * Ec + ve8;
        const float* vp1 = vp0 + Hc * Ec;
        vn00 = ((const float4*)vp0)[0]; vn01 = ((const float4*)vp0)[1];
        vn10 = ((const float4*)vp1)[0]; vn11 = ((const float4*)vp1)[1];
#pragma unroll
        for (int nt = 0; nt < 4; ++nt)
          dn[nt] = deltag[(size_t)b * Sc + nb + nt * 16 + l16];
      }

      // wave-uniform: skip compute for tiles fully above this wave's rows
      const int wtop = q0 + 32 * wave + 31;
      if (kbase <= wtop) {
        // ---- S = Q.K^T (K B-frags read once, shared by both frags) ----
        f32x4 Sacc[2][4];
#pragma unroll
        for (int f = 0; f < 2; ++f)
#pragma unroll
          for (int nt = 0; nt < 4; ++nt) Sacc[f][nt] = (f32x4){0.f, 0.f, 0.f, 0.f};
#pragma unroll
        for (int kk = 0; kk < 2; ++kk) {
          h8 bf[4];
#pragma unroll
          for (int nt = 0; nt < 4; ++nt)
            bf[nt] = *(const h8*)&Ks[cur][(nt * 16 + l16) * LDK + quad * 8 + kk * 32];
#pragma unroll
          for (int f = 0; f < 2; ++f)
#pragma unroll
            for (int nt = 0; nt < 4; ++nt)
              Sacc[f][nt] = __builtin_amdgcn_mfma_f32_16x16x32_f16(qfrag[f][kk], bf[nt], Sacc[f][nt], 0, 0, 0);
        }

        // ---- two passes: softmax(f) -> P(f) -> PV(f) ----
#pragma unroll
        for (int f = 0; f < 2; ++f) {
          const int fr0 = q0 + 32 * wave + 16 * f;
          float sv[4][4];
#pragma unroll
          for (int nt = 0; nt < 4; ++nt)
#pragma unroll
            for (int r = 0; r < 4; ++r)
              sv[nt][r] = Sacc[f][nt][r] * ct + dcur[nt];
          if (kbase + 63 > fr0) {
#pragma unroll
            for (int nt = 0; nt < 4; ++nt) {
              const int key = kbase + nt * 16 + l16;
#pragma unroll
              for (int r = 0; r < 4; ++r)
                if (key > fr0 + quad * 4 + r) sv[nt][r] = -1e30f;
            }
          }
#pragma unroll
          for (int r = 0; r < 4; ++r) {
            float tm = fmaxf(fmaxf(sv[0][r], sv[1][r]), fmaxf(sv[2][r], sv[3][r]));
            tm = rowmax16(tm);
            float mn = fmaxf(mrow[f][r], tm);
            float alpha = __builtin_amdgcn_exp2f(mrow[f][r] - mn);
            mrow[f][r] = mn;
#pragma unroll
            for (int nt = 0; nt < 4; ++nt)
              sv[nt][r] = __builtin_amdgcn_exp2f(sv[nt][r] - mn);
            Osum[f][r] *= alpha;
#pragma unroll
            for (int nt = 0; nt < 4; ++nt) Oacc[f][nt][r] *= alpha;
          }
          // P -> LDS rows quad*4+r (within-wave LDS in-order: WAR safe)
#pragma unroll
          for (int r = 0; r < 4; ++r) {
            float o0 = dpp_f<0xB1>(sv[0][r]);
            float o1 = dpp_f<0xB1>(sv[1][r]);
            float o2 = dpp_f<0xB1>(sv[2][r]);
            float o3 = dpp_f<0xB1>(sv[3][r]);
            h2 d0 = lo ? pk2(o2, sv[2][r]) : pk2(sv[0][r], o0);
            h2 d1 = lo ? pk2(o3, sv[3][r]) : pk2(sv[1][r], o1);
            _Float16* pp = &pb[((quad << 2) + r) * LDK + pbase];
            *(h2*)pp = d0;
            *(h2*)(pp + 16) = d1;
          }
          asm volatile("s_waitcnt lgkmcnt(0)" ::: "memory");  // wave-local P RAW

          h8 af0 = *(const h8*)&pb[l16 * LDK + quad * 8];
          h8 af1 = *(const h8*)&pb[l16 * LDK + quad * 8 + 32];

#pragma unroll
          for (int nt = 0; nt < 4; ++nt) {
            h8 vf0 = *(const h8*)&Vt[cur][(nt * 16 + l16) * LDK + quad * 8];
            Oacc[f][nt] = __builtin_amdgcn_mfma_f32_16x16x32_f16(af0, vf0, Oacc[f][nt], 0, 0, 0);
            h8 vf1 = *(const h8*)&Vt[cur][(nt * 16 + l16) * LDK + quad * 8 + 32];
            Oacc[f][nt] = __builtin_amdgcn_mfma_f32_16x16x32_f16(af1, vf1, Oacc[f][nt], 0, 0, 0);
          }
          Osum[f] = __builtin_amdgcn_mfma_f32_16x16x32_f16(af0, onesf, Osum[f], 0, 0, 0);
          Osum[f] = __builtin_amdgcn_mfma_f32_16x16x32_f16(af1, onesf, Osum[f], 0, 0, 0);
        }
      }

      // ---- write prefetched tile kt+1 into the other buffer ----
      if (pf) {
        _Float16* ksn = &Ks[cur ^ 1][0];
        _Float16* vtn = &Vt[cur ^ 1][0];
        union { h8 v; h2 c[4]; } w0, w1;
        w0.c[0] = pk2(kn0.x, kn0.y); w0.c[1] = pk2(kn0.z, kn0.w);
        w0.c[2] = pk2(kn1.x, kn1.y); w0.c[3] = pk2(kn1.z, kn1.w);
        w1.c[0] = pk2(kn2.x, kn2.y); w1.c[1] = pk2(kn2.z, kn2.w);
        w1.c[2] = pk2(kn3.x, kn3.y); w1.c[3] = pk2(kn3.z, kn3.w);
        *(h8*)&ksn[srow * LDK + sec] = w0.v;
        *(h8*)&ksn[srow * LDK + sec + 8] = w1.v;
        const float e0[8] = {vn00.x, vn00.y, vn00.z, vn00.w, vn01.x, vn01.y, vn01.z, vn01.w};
        const float e1[8] = {vn10.x, vn10.y, vn10.z, vn10.w, vn11.x, vn11.y, vn11.z, vn11.w};
#pragma unroll
        for (int j = 0; j < 8; ++j)
          *(h2*)&vtn[(ve8 + j) * LDK + 2 * vrp] = pk2(e0[j], e1[j]);
#pragma unroll
        for (int nt = 0; nt < 4; ++nt) dcur[nt] = dn[nt] * (SCALE * LOG2E);
      }
    }

    // ---- epilogue ----
    if (nch == 1) {
#pragma unroll
      for (int f = 0; f < 2; ++f)
#pragma unroll
        for (int r = 0; r < 4; ++r) {
          const int qrow = q0 + 32 * wave + 16 * f + (quad << 2) + r;
          const float inv = 1.0f / Osum[f][r];
          float* op = Og + (((size_t)b * Lc + qrow) * Hc + h) * Ec;
#pragma unroll
          for (int nt = 0; nt < 4; ++nt) op[nt * 16 + l16] = Oacc[f][nt][r] * inv;
        }
    } else {
      const int en = bh * EPB + pre_e + c0;
      _Float16* op = Opart + (size_t)en * (QTL * Ec);
#pragma unroll
      for (int f = 0; f < 2; ++f)
#pragma unroll
        for (int r = 0; r < 4; ++r) {
          const int row = 32 * wave + 16 * f + (quad << 2) + r;
#pragma unroll
          for (int nt = 0; nt < 4; ++nt)
            op[row * Ec + nt * 16 + l16] = (_Float16)Oacc[f][nt][r];
          if (l16 == 0) {
            Mpart[en * QTL + row] = mrow[f][r];
            Lpart[en * QTL + row] = Osum[f][r];
          }
        }
    }
  }
}

template <int CH_IT, int EPB>
__global__ __launch_bounds__(256, 4)
void dsattn_comb(const _Float16* __restrict__ Opart, const float* __restrict__ Mpart,
                 const float* __restrict__ Lpart, float* __restrict__ Og) {
  const int qt = (CH_IT / 2) + ((int)blockIdx.x >> 2);  // multi-chunk q-tiles
  const int slab = (int)blockIdx.x & 3;                 // 32-row slab
  const int bh = (int)blockIdx.y;
  const int b = bh >> 3, h = bh & 7;
  const int nch = (2 * qt + 1 + CH_IT) / CH_IT;         // 2..8
  int pre_e = 0;
#pragma unroll
  for (int q = 0; q < NQT; ++q)
    if (q < qt) pre_e += (2 * q + 1 + CH_IT) / CH_IT;
  const int e0 = bh * EPB + pre_e;

  const int row = slab * 32 + ((int)threadIdx.x >> 3);  // 0..127
  const int col = ((int)threadIdx.x & 7) << 3;          // 8 cols per thread

  float ms[8];
  float M = -1e30f;
  for (int c = 0; c < nch; ++c) {
    ms[c] = Mpart[(e0 + c) * QTL + row];
    M = fmaxf(M, ms[c]);
  }
  float acc[8];
#pragma unroll
  for (int i = 0; i < 8; ++i) acc[i] = 0.f;
  float l = 0.f;
  for (int c = 0; c < nch; ++c) {
    const float w = __builtin_amdgcn_exp2f(ms[c] - M);
    l += w * Lpart[(e0 + c) * QTL + row];
    h8 v = *(const h8*)(Opart + (size_t)(e0 + c) * (QTL * Ec) + row * Ec + col);
#pragma unroll
    for (int i = 0; i < 8; ++i) acc[i] += w * (float)v[i];
  }
  const float inv = 1.0f / l;
  float* out = Og + (((size_t)b * Lc + qt * QTL + row) * Hc + h) * Ec + col;
  float4 o0, o1;
  o0.x = acc[0] * inv; o0.y = acc[1] * inv; o0.z = acc[2] * inv; o0.w = acc[3] * inv;
  o1.x = acc[4] * inv; o1.y = acc[5] * inv; o1.z = acc[6] * inv; o1.w = acc[7] * inv;
  ((float4*)out)[0] = o0;
  ((float4*)out)[1] = o1;
}

extern "C" void kernel_launch(void* const* d_in, const int* in_sizes, int n_in,
                              void* d_out, int out_size, void* d_ws, size_t ws_size,
                              hipStream_t stream) {
  const float* Q = (const float*)d_in[0];
  const float* K = (const float*)d_in[1];
  const float* V = (const float*)d_in[2];
  const float* tau = (const float*)d_in[3];
  const float* delta = (const float*)d_in[4];
  float* O = (float*)d_out;

  constexpr int CH = 4;                    // kt-tiles per chunk (256 keys)
  constexpr int EPB = 72;                  // sum of nch over 16 q-tiles
  constexpr int TOT_E = Bc * Hc * EPB;     // 1152 work items
  constexpr int PERS = 768;                // 3 blocks/CU x 256 CUs
  const size_t need = (size_t)TOT_E * QTL * Ec * 2 + 2 * (size_t)TOT_E * QTL * 4;

  if (ws_size >= need) {
    _Float16* Opart = (_Float16*)d_ws;
    float* Mpart = (float*)(Opart + (size_t)TOT_E * QTL * Ec);
    float* Lpart = Mpart + (size_t)TOT_E * QTL;
    dsattn_fwd<CH, EPB, TOT_E><<<dim3(PERS), 256, 0, stream>>>(
        Q, K, V, tau, delta, O, Opart, Mpart, Lpart);
    dim3 g2((NQT - CH / 2) * 4, Bc * Hc);  // 4 row-slabs per multi-chunk q-tile
    dsattn_comb<CH, EPB><<<g2, 256, 0, stream>>>(Opart, Mpart, Lpart, O);
  } else {
    // monolithic fallback: one item per (qt,bh), no workspace
    dsattn_fwd<32, NQT, NQT * NBH><<<dim3(NQT * NBH), 256, 0, stream>>>(
        Q, K, V, tau, delta, O, nullptr, nullptr, nullptr);
  }
}